// Round 9
// baseline (149.742 us; speedup 1.0000x reference)
//
#include <hip/hip_runtime.h>

#define D 4096

typedef float fx4 __attribute__((ext_vector_type(4)));

// ws layout (floats):
//   CS0 = 0      colsum0 [D]  (atomics; memset first)
//   CS1 = D      colsum1 [D]  (atomics; memset first)
//   RS1 = 2D     rowsum1 [D]
//   RS2 = 3D     rowsum2 [D]
//   MSG = 4D     m0,m1,m2,m3 [4][D]
#define CS0 0
#define CS1 D
#define RS1 (2 * D)
#define RS2 (3 * D)
#define MSG (4 * D)

// ---------------- pass 1: reductions (R3-proven, unchanged) ----------------
__global__ void __launch_bounds__(256) reduce_all_kernel(
        const float* __restrict__ t0, const float* __restrict__ t1,
        const float* __restrict__ t2, float* __restrict__ ws) {
    int b = blockIdx.x;
    if (b < 512) {
        const float* A = (b < 256) ? t0 : t1;
        float* out = ws + ((b < 256) ? CS0 : CS1);
        int lb = b & 255;
        int c4 = (lb & 3) * 256 + threadIdx.x;     // fx4-column 0..1023
        int r0 = (lb >> 2) * 64;                   // 64-row stripe
        const fx4* A4 = (const fx4*)A;
        fx4 s = (fx4){0.f, 0.f, 0.f, 0.f};
        #pragma unroll 8
        for (int r = 0; r < 64; ++r)
            s += A4[(size_t)(r0 + r) * (D / 4) + c4];
        atomicAdd(&out[c4 * 4 + 0], s.x);
        atomicAdd(&out[c4 * 4 + 1], s.y);
        atomicAdd(&out[c4 * 4 + 2], s.z);
        atomicAdd(&out[c4 * 4 + 3], s.w);
    } else {
        int lb = (b - 512) & 1023;                 // 0..1023
        const float* A = (b < 1536) ? t1 : t2;
        float* out = ws + ((b < 1536) ? RS1 : RS2);
        int wid = threadIdx.x >> 6, lane = threadIdx.x & 63;
        int row = lb * 4 + wid;
        const fx4* R = (const fx4*)(A + (size_t)row * D);
        float s = 0.f;
        #pragma unroll
        for (int j = 0; j < 16; ++j) {
            fx4 v = R[lane + 64 * j];
            s += (v.x + v.y) + (v.z + v.w);
        }
        #pragma unroll
        for (int o = 32; o > 0; o >>= 1) s += __shfl_down(s, o);
        if (lane == 0) out[row] = s;
    }
}

// ---------------- pass 2: message chain (single block, R3-proven) ----------------

__device__ __forceinline__ float block_sum_1024(float v, float* red) {
    #pragma unroll
    for (int o = 32; o > 0; o >>= 1) v += __shfl_down(v, o);
    int lane = threadIdx.x & 63, wid = threadIdx.x >> 6;
    if (lane == 0) red[wid] = v;
    __syncthreads();
    if (threadIdx.x == 0) {
        float t = 0.f;
        #pragma unroll
        for (int w = 0; w < 16; ++w) t += red[w];
        red[0] = t;
    }
    __syncthreads();
    float r = red[0];
    __syncthreads();
    return r;
}

__global__ void __launch_bounds__(1024) messages_kernel(
        const float* __restrict__ ws,
        const int* __restrict__ op0, const int* __restrict__ op1,
        const int* __restrict__ op2, const int* __restrict__ op3,
        float* __restrict__ ws_w) {
    __shared__ float m0[D], m1[D], m2[D], m3[D];
    __shared__ float red[16];
    int tid = threadIdx.x;

    int s0[4], d0[4], s1[4], d1[4], s2[4], d2[4], s3[4], d3[4];
    #pragma unroll
    for (int k = 0; k < 4; ++k) {
        int i = tid + k * 1024;
        s0[k] = op0[i]; d0[k] = op0[D + i];
        s1[k] = op1[i]; d1[k] = op1[D + i];
        s2[k] = op2[i]; d2[k] = op2[D + i];
        s3[k] = op3[i]; d3[k] = op3[D + i];
    }
    float g0[4], g1[4], g2[4], g3[4];
    #pragma unroll
    for (int k = 0; k < 4; ++k) {
        g0[k] = ws[CS0 + s0[k]];
        g1[k] = ws[CS1 + s1[k]];
        g2[k] = ws[RS2 + s2[k]];
        g3[k] = ws[RS1 + s3[k]];
    }

    #pragma unroll
    for (int k = 0; k < 4; ++k) {
        int i = tid + k * 1024;
        m0[i] = 0.f; m1[i] = 0.f; m2[i] = 0.f; m3[i] = 0.f;
    }
    __syncthreads();

    #pragma unroll
    for (int k = 0; k < 4; ++k) atomicAdd(&m0[d0[k]], g0[k]);
    __syncthreads();

    float p = 0.f;
    #pragma unroll
    for (int k = 0; k < 4; ++k) p += m0[tid + k * 1024];
    float S0 = block_sum_1024(p, red);

    #pragma unroll
    for (int k = 0; k < 4; ++k) atomicAdd(&m1[d1[k]], g1[k] + S0);
    __syncthreads();

    #pragma unroll
    for (int k = 0; k < 4; ++k)
        atomicAdd(&m2[d2[k]], g2[k] + 4095.0f * m1[s2[k]]);
    __syncthreads();

    p = 0.f;
    #pragma unroll
    for (int k = 0; k < 4; ++k) p += m2[tid + k * 1024];
    float S2 = block_sum_1024(p, red);

    #pragma unroll
    for (int k = 0; k < 4; ++k)
        atomicAdd(&m3[d3[k]], g3[k] + 4095.0f * m0[s3[k]] + S2);
    __syncthreads();

    #pragma unroll
    for (int k = 0; k < 4; ++k) {
        int i = tid + k * 1024;
        ws_w[MSG + 0 * D + i] = m0[i];
        ws_w[MSG + 1 * D + i] = m1[i];
        ws_w[MSG + 2 * D + i] = m2[i];
        ws_w[MSG + 3 * D + i] = m3[i];
    }
}

// ---------------- pass 3: apply broadcasts, one matrix per launch ----------------
// PLAIN loads (allow IC hits on the theta re-read); nt stores (bypass caches).
// mode 0: out0 = t + m3[col]; mode 1: out1 = t + m0[row] + m2[col]; mode 2: out2 = t + m1[row].

template <int MODE>
__global__ void __launch_bounds__(256) apply_one_kernel(
        const float* __restrict__ t, const float* __restrict__ msgs,
        float* __restrict__ outm) {
    int row = blockIdx.x;
    size_t base = (size_t)row * D;
    const fx4* src = (const fx4*)(t + base);
    fx4* dst = (fx4*)(outm + base);

    if (MODE == 0) {
        const fx4* c4 = (const fx4*)(msgs + 3 * D);     // m3 over columns
        for (int i = threadIdx.x; i < D / 4; i += 256) {
            fx4 r = src[i] + c4[i];
            __builtin_nontemporal_store(r, &dst[i]);
        }
    } else if (MODE == 1) {
        const fx4* c4 = (const fx4*)(msgs + 2 * D);     // m2 over columns
        float rr = msgs[0 * D + row];                   // m0 over rows
        for (int i = threadIdx.x; i < D / 4; i += 256) {
            fx4 r = src[i] + c4[i] + rr;
            __builtin_nontemporal_store(r, &dst[i]);
        }
    } else {
        float rr = msgs[1 * D + row];                   // m1 over rows
        for (int i = threadIdx.x; i < D / 4; i += 256) {
            fx4 r = src[i] + rr;
            __builtin_nontemporal_store(r, &dst[i]);
        }
    }
}

extern "C" void kernel_launch(void* const* d_in, const int* in_sizes, int n_in,
                              void* d_out, int out_size, void* d_ws, size_t ws_size,
                              hipStream_t stream) {
    const float* t0 = (const float*)d_in[0];
    const float* t1 = (const float*)d_in[1];
    const float* t2 = (const float*)d_in[2];
    const int* op0 = (const int*)d_in[3];
    const int* op1 = (const int*)d_in[4];
    const int* op2 = (const int*)d_in[5];
    const int* op3 = (const int*)d_in[6];
    float* out = (float*)d_out;
    float* ws = (float*)d_ws;

    hipMemsetAsync(ws, 0, 2 * D * sizeof(float), stream);

    reduce_all_kernel<<<2560, 256, 0, stream>>>(t0, t1, t2, ws);
    messages_kernel<<<1, 1024, 0, stream>>>(ws, op0, op1, op2, op3, ws);
    // t2 first (freshest), then t1, then t0
    apply_one_kernel<2><<<D, 256, 0, stream>>>(t2, ws + MSG, out + 2 * (size_t)D * D);
    apply_one_kernel<1><<<D, 256, 0, stream>>>(t1, ws + MSG, out + 1 * (size_t)D * D);
    apply_one_kernel<0><<<D, 256, 0, stream>>>(t0, ws + MSG, out + 0 * (size_t)D * D);
}

// Round 10
// 135.081 us; speedup vs baseline: 1.1085x; 1.1085x over previous
//
#include <hip/hip_runtime.h>

#define D 4096

typedef float fx4 __attribute__((ext_vector_type(4)));

// ws layout (floats):
//   CS0=0 colsum0[D] (atomics; memset)   CS1=D colsum1[D] (atomics; memset)
//   RS1=2D rowsum1[D] (by applyT1)       RS2=3D rowsum2[D] (by applyT2)
//   M0=4D M1=5D M2=6D M3=7D  messages    S2S=8D  S2 scalar
#define CS0 0
#define CS1 D
#define RS1 (2 * D)
#define RS2 (3 * D)
#define M0O (4 * D)
#define M1O (5 * D)
#define M2O (6 * D)
#define M3O (7 * D)
#define S2S (8 * D)

// ---------------- K1: colsums of t0,t1 (R3-proven geometry) ----------------
// 512 blocks x 256: [0,256) t0 -> CS0, [256,512) t1 -> CS1.
__global__ void __launch_bounds__(256) colsum_kernel(
        const float* __restrict__ t0, const float* __restrict__ t1,
        float* __restrict__ ws) {
    int b = blockIdx.x;
    const float* A = (b < 256) ? t0 : t1;
    float* out = ws + ((b < 256) ? CS0 : CS1);
    int lb = b & 255;
    int c4 = (lb & 3) * 256 + threadIdx.x;     // fx4-column 0..1023
    int r0 = (lb >> 2) * 64;                   // 64-row stripe
    const fx4* A4 = (const fx4*)A;
    fx4 s = (fx4){0.f, 0.f, 0.f, 0.f};
    #pragma unroll 8
    for (int r = 0; r < 64; ++r)
        s += A4[(size_t)(r0 + r) * (D / 4) + c4];
    atomicAdd(&out[c4 * 4 + 0], s.x);
    atomicAdd(&out[c4 * 4 + 1], s.y);
    atomicAdd(&out[c4 * 4 + 2], s.z);
    atomicAdd(&out[c4 * 4 + 3], s.w);
}

// ---------------- single-block message kernels ----------------

__device__ __forceinline__ float block_sum_1024(float v, float* red) {
    #pragma unroll
    for (int o = 32; o > 0; o >>= 1) v += __shfl_down(v, o);
    int lane = threadIdx.x & 63, wid = threadIdx.x >> 6;
    if (lane == 0) red[wid] = v;
    __syncthreads();
    if (threadIdx.x == 0) {
        float t = 0.f;
        #pragma unroll
        for (int w = 0; w < 16; ++w) t += red[w];
        red[0] = t;
    }
    __syncthreads();
    float r = red[0];
    __syncthreads();
    return r;
}

// msgsA: m0 = remap(CS0, op0); S0 = sum(m0); m1 = remap(CS1 + S0, op1)
__global__ void __launch_bounds__(1024) msgsA_kernel(
        float* __restrict__ ws, const int* __restrict__ op0,
        const int* __restrict__ op1) {
    __shared__ float m0[D], m1[D];
    __shared__ float red[16];
    int tid = threadIdx.x;

    int s0[4], d0[4], s1[4], d1[4];
    #pragma unroll
    for (int k = 0; k < 4; ++k) {
        int i = tid + k * 1024;
        s0[k] = op0[i]; d0[k] = op0[D + i];
        s1[k] = op1[i]; d1[k] = op1[D + i];
    }
    float g0[4], g1[4];
    #pragma unroll
    for (int k = 0; k < 4; ++k) {
        g0[k] = ws[CS0 + s0[k]];
        g1[k] = ws[CS1 + s1[k]];
    }
    #pragma unroll
    for (int k = 0; k < 4; ++k) {
        int i = tid + k * 1024;
        m0[i] = 0.f; m1[i] = 0.f;
    }
    __syncthreads();
    #pragma unroll
    for (int k = 0; k < 4; ++k) atomicAdd(&m0[d0[k]], g0[k]);
    __syncthreads();
    float p = 0.f;
    #pragma unroll
    for (int k = 0; k < 4; ++k) p += m0[tid + k * 1024];
    float S0 = block_sum_1024(p, red);
    #pragma unroll
    for (int k = 0; k < 4; ++k) atomicAdd(&m1[d1[k]], g1[k] + S0);
    __syncthreads();
    #pragma unroll
    for (int k = 0; k < 4; ++k) {
        int i = tid + k * 1024;
        ws[M0O + i] = m0[i];
        ws[M1O + i] = m1[i];
    }
}

// msgsB: m2 = remap(RS2 + 4095*m1, op2); S2 = sum(m2)
__global__ void __launch_bounds__(1024) msgsB_kernel(
        float* __restrict__ ws, const int* __restrict__ op2) {
    __shared__ float m2[D];
    __shared__ float red[16];
    int tid = threadIdx.x;

    int s2[4], d2[4];
    #pragma unroll
    for (int k = 0; k < 4; ++k) {
        int i = tid + k * 1024;
        s2[k] = op2[i]; d2[k] = op2[D + i];
    }
    float g2[4];
    #pragma unroll
    for (int k = 0; k < 4; ++k)
        g2[k] = ws[RS2 + s2[k]] + 4095.0f * ws[M1O + s2[k]];
    #pragma unroll
    for (int k = 0; k < 4; ++k) m2[tid + k * 1024] = 0.f;
    __syncthreads();
    #pragma unroll
    for (int k = 0; k < 4; ++k) atomicAdd(&m2[d2[k]], g2[k]);
    __syncthreads();
    float p = 0.f;
    #pragma unroll
    for (int k = 0; k < 4; ++k) p += m2[tid + k * 1024];
    float S2 = block_sum_1024(p, red);
    #pragma unroll
    for (int k = 0; k < 4; ++k) {
        int i = tid + k * 1024;
        ws[M2O + i] = m2[i];
    }
    if (tid == 0) ws[S2S] = S2;
}

// msgsC: m3 = remap(RS1 + 4095*m0 + S2, op3)
__global__ void __launch_bounds__(1024) msgsC_kernel(
        float* __restrict__ ws, const int* __restrict__ op3) {
    __shared__ float m3[D];
    int tid = threadIdx.x;

    int s3[4], d3[4];
    #pragma unroll
    for (int k = 0; k < 4; ++k) {
        int i = tid + k * 1024;
        s3[k] = op3[i]; d3[k] = op3[D + i];
    }
    float S2 = ws[S2S];
    float g3[4];
    #pragma unroll
    for (int k = 0; k < 4; ++k)
        g3[k] = ws[RS1 + s3[k]] + 4095.0f * ws[M0O + s3[k]] + S2;
    #pragma unroll
    for (int k = 0; k < 4; ++k) m3[tid + k * 1024] = 0.f;
    __syncthreads();
    #pragma unroll
    for (int k = 0; k < 4; ++k) atomicAdd(&m3[d3[k]], g3[k]);
    __syncthreads();
    #pragma unroll
    for (int k = 0; k < 4; ++k) {
        int i = tid + k * 1024;
        ws[M3O + i] = m3[i];
    }
}

// ---------------- apply kernels (1 row per 256-thread block) ----------------
// rowsum (of the ORIGINAL theta values) fused where needed.

__device__ __forceinline__ void row_reduce_store(float s, float* dst) {
    __shared__ float red[4];
    #pragma unroll
    for (int o = 32; o > 0; o >>= 1) s += __shfl_down(s, o);
    int lane = threadIdx.x & 63, wid = threadIdx.x >> 6;
    if (lane == 0) red[wid] = s;
    __syncthreads();
    if (threadIdx.x == 0) *dst = (red[0] + red[1]) + (red[2] + red[3]);
}

// out2 = t2 + m1[row]; RS2[row] = rowsum(t2 row)
__global__ void __launch_bounds__(256) applyT2_kernel(
        const float* __restrict__ t2, float* __restrict__ ws,
        float* __restrict__ out2) {
    int row = blockIdx.x;
    size_t base = (size_t)row * D;
    const fx4* src = (const fx4*)(t2 + base);
    fx4* dst = (fx4*)(out2 + base);
    float rr = ws[M1O + row];

    fx4 v[4];
    float s = 0.f;
    #pragma unroll
    for (int k = 0; k < 4; ++k) {
        v[k] = src[threadIdx.x + 256 * k];
        s += (v[k].x + v[k].y) + (v[k].z + v[k].w);
    }
    #pragma unroll
    for (int k = 0; k < 4; ++k)
        __builtin_nontemporal_store(v[k] + rr, &dst[threadIdx.x + 256 * k]);
    row_reduce_store(s, ws + RS2 + row);
}

// out1 = t1 + m0[row] + m2[col]; RS1[row] = rowsum(t1 row)
__global__ void __launch_bounds__(256) applyT1_kernel(
        const float* __restrict__ t1, float* __restrict__ ws,
        float* __restrict__ out1) {
    int row = blockIdx.x;
    size_t base = (size_t)row * D;
    const fx4* src = (const fx4*)(t1 + base);
    const fx4* c4 = (const fx4*)(ws + M2O);
    fx4* dst = (fx4*)(out1 + base);
    float rr = ws[M0O + row];

    fx4 v[4], c[4];
    float s = 0.f;
    #pragma unroll
    for (int k = 0; k < 4; ++k) {
        v[k] = src[threadIdx.x + 256 * k];
        c[k] = c4[threadIdx.x + 256 * k];
        s += (v[k].x + v[k].y) + (v[k].z + v[k].w);
    }
    #pragma unroll
    for (int k = 0; k < 4; ++k)
        __builtin_nontemporal_store(v[k] + c[k] + rr,
                                    &dst[threadIdx.x + 256 * k]);
    row_reduce_store(s, ws + RS1 + row);
}

// out0 = t0 + m3[col]
__global__ void __launch_bounds__(256) applyT0_kernel(
        const float* __restrict__ t0, const float* __restrict__ ws,
        float* __restrict__ out0) {
    int row = blockIdx.x;
    size_t base = (size_t)row * D;
    const fx4* src = (const fx4*)(t0 + base);
    const fx4* c4 = (const fx4*)(ws + M3O);
    fx4* dst = (fx4*)(out0 + base);

    #pragma unroll
    for (int k = 0; k < 4; ++k) {
        fx4 r = src[threadIdx.x + 256 * k] + c4[threadIdx.x + 256 * k];
        __builtin_nontemporal_store(r, &dst[threadIdx.x + 256 * k]);
    }
}

extern "C" void kernel_launch(void* const* d_in, const int* in_sizes, int n_in,
                              void* d_out, int out_size, void* d_ws, size_t ws_size,
                              hipStream_t stream) {
    const float* t0 = (const float*)d_in[0];
    const float* t1 = (const float*)d_in[1];
    const float* t2 = (const float*)d_in[2];
    const int* op0 = (const int*)d_in[3];
    const int* op1 = (const int*)d_in[4];
    const int* op2 = (const int*)d_in[5];
    const int* op3 = (const int*)d_in[6];
    float* out = (float*)d_out;
    float* ws = (float*)d_ws;

    hipMemsetAsync(ws, 0, 2 * D * sizeof(float), stream);     // CS0, CS1

    colsum_kernel<<<512, 256, 0, stream>>>(t0, t1, ws);       // 128 MB
    msgsA_kernel<<<1, 1024, 0, stream>>>(ws, op0, op1);       // m0, m1
    applyT2_kernel<<<D, 256, 0, stream>>>(t2, ws, out + 2 * (size_t)D * D);  // t2 1x
    msgsB_kernel<<<1, 1024, 0, stream>>>(ws, op2);            // m2, S2
    applyT1_kernel<<<D, 256, 0, stream>>>(t1, ws, out + 1 * (size_t)D * D);  // t1 2nd
    msgsC_kernel<<<1, 1024, 0, stream>>>(ws, op3);            // m3
    applyT0_kernel<<<D, 256, 0, stream>>>(t0, ws, out + 0 * (size_t)D * D);  // t0 2nd
}